// Round 4
// baseline (169.814 us; speedup 1.0000x reference)
//
#include <hip/hip_runtime.h>

#define NN   100000
#define KK   32
#define DIN  128
#define DOUT 64
#define NEGV (-9e15f)

typedef __attribute__((ext_vector_type(8))) short bf16x8;   // 4 VGPRs
typedef __attribute__((ext_vector_type(4))) float f32x4;

__device__ __forceinline__ float bflo(unsigned u) { return __uint_as_float(u << 16); }
__device__ __forceinline__ float bfhi(unsigned u) { return __uint_as_float(u & 0xffff0000u); }
__device__ __forceinline__ ushort f2bf(float f) {            // round-to-nearest-even
    unsigned u = __float_as_uint(f);
    return (ushort)((u + 0x7fffu + ((u >> 16) & 1u)) >> 16);
}
__device__ __forceinline__ unsigned pk2(float a, float b) {  // [bf16(a) | bf16(b)<<16]
    unsigned r;
    asm("v_cvt_pk_bf16_f32 %0, %1, %2" : "=v"(r) : "v"(a), "v"(b));
    return r;
}
__device__ __forceinline__ bf16x8 cvt8(float4 a, float4 b) {
    union { unsigned u[4]; bf16x8 v; } r;
    r.u[0] = pk2(a.x, a.y); r.u[1] = pk2(a.z, a.w);
    r.u[2] = pk2(b.x, b.y); r.u[3] = pk2(b.z, b.w);
    return r.v;
}

// ---------------------------------------------------------------------------
// Kernel A (MFMA): hb = bf16(x @ W^T + b), hb[0][:] = bf16(NEGV)
// Unchanged from round 3 (fell below top-5). No LDS; A from global x with
// in-reg f32->bf16 cvt; B (W) in 64 VGPRs; bias folded at store.
// ---------------------------------------------------------------------------
__global__ __launch_bounds__(256) void h_kernel(const float* __restrict__ x,
                                                const float* __restrict__ W,
                                                const float* __restrict__ b,
                                                ushort* __restrict__ hb) {
    const int t    = threadIdx.x;
    const int w    = t >> 6;
    const int lane = t & 63;
    const int lr   = lane & 15;     // frag row (A) / col (B, C)
    const int lg   = lane >> 4;     // k-group

    bf16x8 Bf[4][4];
    const float* wp = W + (size_t)lr * DIN + lg * 8;
#pragma unroll
    for (int ct = 0; ct < 4; ++ct)
#pragma unroll
        for (int ks = 0; ks < 4; ++ks) {
            const float* p = wp + ct * 16 * DIN + ks * 32;
            Bf[ct][ks] = cvt8(*(const float4*)p, *(const float4*)(p + 4));
        }

    float bias[4];
#pragma unroll
    for (int ct = 0; ct < 4; ++ct) bias[ct] = b[ct * 16 + lr];

    const int base = blockIdx.x * 128 + w * 16;
#pragma unroll
    for (int tile = 0; tile < 2; ++tile) {
        const int row0 = base + tile * 64;

        int ar = row0 + lr;
        if (ar > NN - 1) ar = NN - 1;
        const float* xp = x + (size_t)ar * DIN + lg * 8;

        bf16x8 Af[4];
#pragma unroll
        for (int ks = 0; ks < 4; ++ks)
            Af[ks] = cvt8(*(const float4*)(xp + ks * 32),
                          *(const float4*)(xp + ks * 32 + 4));

        f32x4 acc[4] = {{0.f,0.f,0.f,0.f},{0.f,0.f,0.f,0.f},
                        {0.f,0.f,0.f,0.f},{0.f,0.f,0.f,0.f}};
#pragma unroll
        for (int ct = 0; ct < 4; ++ct)
#pragma unroll
            for (int ks = 0; ks < 4; ++ks)
                acc[ct] = __builtin_amdgcn_mfma_f32_16x16x32_bf16(
                    Af[ks], Bf[ct][ks], acc[ct], 0, 0, 0);

#pragma unroll
        for (int ct = 0; ct < 4; ++ct)
#pragma unroll
            for (int j = 0; j < 4; ++j) {
                const int m = row0 + lg * 4 + j;
                if (m < NN) {
                    const float v = (m == 0) ? NEGV : (acc[ct][j] + bias[ct]);
                    hb[(size_t)m * DOUT + ct * 16 + lr] = f2bf(v);
                }
            }
    }
}

// ---------------------------------------------------------------------------
// Kernel B (MFMA gather-attention): per row n, the 32 neighbor dots are a
// 32x64 . 64 matvec -> 4 x mfma_f32_16x16x32_bf16.
//   A tile t, kstep s: lane holds hb[nbr[t*16 + (l&15)]][s*32 + (l>>4)*8 + j]
//   B: h[n] broadcast into ALL 16 columns (B[k][c] = h[n][k] for every c),
//      so D[r][c] is the same dot in every column -> no extraction shuffles.
//   D: lane holds dots of neighbors t*16 + (l>>4)*4 + {0..3}.
// All reductions collapse to shfl_xor(16) + shfl_xor(32) over the 4 k-groups.
// 2 rows per wave (unrolled) for gather-latency ILP.
// ---------------------------------------------------------------------------
__global__ __launch_bounds__(256) void att_kernel(const ushort* __restrict__ hb,
                                                  const int* __restrict__ a2a,
                                                  float* __restrict__ out) {
    const int t    = threadIdx.x;
    const int wid  = t >> 6;
    const int lane = t & 63;
    const int lr   = lane & 15;
    const int lg   = lane >> 4;
    const int n0   = blockIdx.x * 8 + wid * 2;      // 12500 blocks * 8 rows

#pragma unroll
    for (int r = 0; r < 2; ++r) {
        const int n = n0 + r;
        const ushort* hbn = hb + (size_t)n * DOUT;

        // B fragments: h[n][lg*8..+8] and h[n][32+lg*8..+8], col-duplicated
        const bf16x8 B0 = *(const bf16x8*)(hbn + lg * 8);
        const bf16x8 B1 = *(const bf16x8*)(hbn + 32 + lg * 8);

        // neighbor indices for the two 16-row tiles
        const int i0 = a2a[n * KK + lr];
        const int i1 = a2a[n * KK + 16 + lr];
        const ushort* p0 = hb + (size_t)i0 * DOUT + lg * 8;
        const ushort* p1 = hb + (size_t)i1 * DOUT + lg * 8;

        const bf16x8 A00 = *(const bf16x8*)p0;         // tile0, k 0..31
        const bf16x8 A01 = *(const bf16x8*)(p0 + 32);  // tile0, k 32..63
        const bf16x8 A10 = *(const bf16x8*)p1;         // tile1, k 0..31
        const bf16x8 A11 = *(const bf16x8*)(p1 + 32);  // tile1, k 32..63

        const float hv = bflo((unsigned)hbn[lane]);    // own value for output

        f32x4 d0 = {0.f, 0.f, 0.f, 0.f};
        f32x4 d1 = {0.f, 0.f, 0.f, 0.f};
        d0 = __builtin_amdgcn_mfma_f32_16x16x32_bf16(A00, B0, d0, 0, 0, 0);
        d0 = __builtin_amdgcn_mfma_f32_16x16x32_bf16(A01, B1, d0, 0, 0, 0);
        d1 = __builtin_amdgcn_mfma_f32_16x16x32_bf16(A10, B0, d1, 0, 0, 0);
        d1 = __builtin_amdgcn_mfma_f32_16x16x32_bf16(A11, B1, d1, 0, 0, 0);

        // self-dot from the B fragments (per-lane 16 elems, reduce k-groups)
        union { bf16x8 v; unsigned u[4]; } ub0, ub1;
        ub0.v = B0; ub1.v = B1;
        float sp = 0.f;
#pragma unroll
        for (int i = 0; i < 4; ++i) {
            float a = bflo(ub0.u[i]), c = bfhi(ub0.u[i]);
            float e = bflo(ub1.u[i]), g = bfhi(ub1.u[i]);
            sp = fmaf(a, a, sp); sp = fmaf(c, c, sp);
            sp = fmaf(e, e, sp); sp = fmaf(g, g, sp);
        }
        sp += __shfl_xor(sp, 16);
        sp += __shfl_xor(sp, 32);

        // max over the 8 per-lane dots, then across k-groups, then self
        float m = fmaxf(fmaxf(fmaxf(d0[0], d0[1]), fmaxf(d0[2], d0[3])),
                        fmaxf(fmaxf(d1[0], d1[1]), fmaxf(d1[2], d1[3])));
        m = fmaxf(m, __shfl_xor(m, 16));
        m = fmaxf(m, __shfl_xor(m, 32));
        m = fmaxf(m, sp);

        // sum of exp (per-lane 8 dots; lanes within a k-group duplicate
        // across columns, so reducing over lg only (xor16,xor32) is exact)
        float s = __expf(d0[0] - m) + __expf(d0[1] - m) +
                  __expf(d0[2] - m) + __expf(d0[3] - m) +
                  __expf(d1[0] - m) + __expf(d1[1] - m) +
                  __expf(d1[2] - m) + __expf(d1[3] - m);
        s += __shfl_xor(s, 16);
        s += __shfl_xor(s, 32);

        const float es = __expf(sp - m);
        const float w0 = es / (es + s);

        float o = hv * w0;
        if (n == 0) o = 0.f;
        out[(size_t)n * DOUT + lane] = o;
    }
}

extern "C" void kernel_launch(void* const* d_in, const int* in_sizes, int n_in,
                              void* d_out, int out_size, void* d_ws, size_t ws_size,
                              hipStream_t stream) {
    const float* x   = (const float*)d_in[0];
    const int*   a2a = (const int*)d_in[1];
    const float* W   = (const float*)d_in[2];
    const float* b   = (const float*)d_in[3];
    float*       out = (float*)d_out;
    ushort*      hb  = (ushort*)d_ws;   // N*DOUT*2 = 12.8 MB bf16 table

    h_kernel<<<(NN + 127) / 128, 256, 0, stream>>>(x, W, b, hb);
    att_kernel<<<NN / 8, 256, 0, stream>>>(hb, a2a, out);
}